// Round 6
// baseline (1110.904 us; speedup 1.0000x reference)
//
#include <hip/hip_runtime.h>
#include <hip/hip_bf16.h>

// Problem constants. Harness: fp32 inputs, fp32 output buffer,
// bf16-lenient comparison threshold (2% of max|ref|).
constexpr int BB = 2;
constexpr int SS = 2048;
constexpr int EMBED = 2048;
constexpr int NH = 32;
constexpr int NKV = 8;
constexpr int HD = 64;
constexpr int WIN = 128;      // sliding window
constexpr int M_ROWS = BB * SS;          // 4096
constexpr float SCALE = 0.125f;          // HD^-0.5

typedef __bf16 bf16x8 __attribute__((ext_vector_type(8)));
typedef float f32x4 __attribute__((ext_vector_type(4)));

__device__ inline uint4 cvt8(float4 lo, float4 hi) {
    union { __hip_bfloat16 h[8]; uint4 u; } r;
    r.h[0] = __hip_bfloat16(lo.x); r.h[1] = __hip_bfloat16(lo.y);
    r.h[2] = __hip_bfloat16(lo.z); r.h[3] = __hip_bfloat16(lo.w);
    r.h[4] = __hip_bfloat16(hi.x); r.h[5] = __hip_bfloat16(hi.y);
    r.h[6] = __hip_bfloat16(hi.z); r.h[7] = __hip_bfloat16(hi.w);
    return r.u;
}

// Load 8 contiguous elements as bf16x8-packed uint4.
__device__ inline uint4 load8(const float* p) {
    float4 lo = *(const float4*)p;
    float4 hi = *(const float4*)(p + 4);
    return cvt8(lo, hi);
}
__device__ inline uint4 load8(const __hip_bfloat16* p) {
    return *(const uint4*)p;
}

// ---------------------------------------------------------------------------
// C[M][N] = A[M][K] * B[N][K]^T.  A,B fp32 or bf16 in HBM (converted to bf16
// during LDS staging when fp32); fp32 MFMA accum; TC out (float or bf16).
// Block = 256 threads = 4 waves. Tile 64x64, BK=32.
// ---------------------------------------------------------------------------
template <typename TA, typename TB, typename TC>
__global__ __launch_bounds__(256) void gemm_bt(
    const TA* __restrict__ A,
    const TB* __restrict__ Bm,
    TC* __restrict__ C,
    int M, int N, int K)
{
    __shared__ uint4 As[4 * 64];   // [quad][row] : A[row][k0+quad*8 .. +8] as bf16
    __shared__ uint4 Bs[4 * 64];

    const int t = threadIdx.x;
    const int lane = t & 63;
    const int w = t >> 6;
    const int wr = (w >> 1) * 32;   // wave row quadrant
    const int wc = (w & 1) * 32;    // wave col quadrant
    const int srow = t & 63;        // staging role
    const int squad = t >> 6;
    const long blockM = (long)blockIdx.y * 64;
    const long blockN = (long)blockIdx.x * 64;

    f32x4 acc[2][2] = {};

    const TA* Arow = A + (blockM + srow) * (long)K + squad * 8;
    const TB* Brow = Bm + (blockN + srow) * (long)K + squad * 8;

    const int lquad = lane >> 4;
    const int lrow = lane & 15;

    for (int k0 = 0; k0 < K; k0 += 32) {
        As[squad * 64 + srow] = load8(Arow + k0);
        Bs[squad * 64 + srow] = load8(Brow + k0);
        __syncthreads();

        bf16x8 a0 = *(const bf16x8*)&As[lquad * 64 + wr + lrow];
        bf16x8 a1 = *(const bf16x8*)&As[lquad * 64 + wr + 16 + lrow];
        bf16x8 b0 = *(const bf16x8*)&Bs[lquad * 64 + wc + lrow];
        bf16x8 b1 = *(const bf16x8*)&Bs[lquad * 64 + wc + 16 + lrow];

        acc[0][0] = __builtin_amdgcn_mfma_f32_16x16x32_bf16(a0, b0, acc[0][0], 0, 0, 0);
        acc[0][1] = __builtin_amdgcn_mfma_f32_16x16x32_bf16(a0, b1, acc[0][1], 0, 0, 0);
        acc[1][0] = __builtin_amdgcn_mfma_f32_16x16x32_bf16(a1, b0, acc[1][0], 0, 0, 0);
        acc[1][1] = __builtin_amdgcn_mfma_f32_16x16x32_bf16(a1, b1, acc[1][1], 0, 0, 0);
        __syncthreads();
    }

    // C/D layout: col = lane&15, row = (lane>>4)*4 + reg
    for (int mi = 0; mi < 2; mi++) {
        for (int ni = 0; ni < 2; ni++) {
            for (int r = 0; r < 4; r++) {
                long rr = blockM + wr + mi * 16 + lquad * 4 + r;
                long cc = blockN + wc + ni * 16 + lrow;
                C[rr * N + cc] = TC(acc[mi][ni][r]);
            }
        }
    }
}

// ---------------------------------------------------------------------------
// Per-head RMSNorm + RoPE, in place on bf16 intermediates. fp32 weights.
// One wave per (b,s,head) row of 64.
// ---------------------------------------------------------------------------
__global__ __launch_bounds__(256) void norm_rope(
    __hip_bfloat16* __restrict__ q,
    __hip_bfloat16* __restrict__ k,
    const float* __restrict__ qw,
    const float* __restrict__ kw)
{
    const int QROWS = BB * SS * NH;     // 131072
    int gid = blockIdx.x * 4 + (threadIdx.x >> 6);
    int lane = threadIdx.x & 63;

    __hip_bfloat16* base;
    const float* wptr;
    int s;
    if (gid < QROWS) {
        base = q + (long)gid * HD;
        s = (gid / NH) % SS;
        wptr = qw;
    } else {
        int g = gid - QROWS;
        base = k + (long)g * HD;
        s = (g / NKV) % SS;
        wptr = kw;
    }

    float x = (float)base[lane];
    float ss = x * x;
    for (int off = 32; off; off >>= 1) ss += __shfl_xor(ss, off);
    float scale = rsqrtf(ss * (1.0f / 64.0f) + 1e-6f);
    float xn = x * scale * wptr[lane];

    float partner = __shfl_xor(xn, 32);
    int i = lane & 31;
    float ang = (float)s * powf(10000.0f, -(float)i * (1.0f / 32.0f));
    float sn, cs;
    sincosf(ang, &sn, &cs);
    float y = (lane < 32) ? (xn * cs - partner * sn) : (xn * cs + partner * sn);
    base[lane] = __hip_bfloat16(y);
}

// ---------------------------------------------------------------------------
// Sliding-window attention with sink. One block per (b, h, 64-row q-tile).
// K staged transposed [d][j] so lanes->keys reads are contiguous.
// ---------------------------------------------------------------------------
constexpr int SPAN = 192;   // key span for a 64-row tile: [q0-127, q0+63]

__global__ __launch_bounds__(256) void attn(
    const __hip_bfloat16* __restrict__ q,
    const __hip_bfloat16* __restrict__ k,
    const __hip_bfloat16* __restrict__ v,
    const int* __restrict__ amask,
    const float* __restrict__ sinks,
    __hip_bfloat16* __restrict__ ao)
{
    __shared__ __hip_bfloat16 Kt[64][SPAN + 2];   // [d][j]
    __shared__ __hip_bfloat16 Vs[SPAN][HD + 1];   // [j][d]
    __shared__ __hip_bfloat16 Ql[64][HD + 1];     // [r][d]
    __shared__ float Pl[4][128];                  // per-wave probs

    const int bid = blockIdx.x;
    const int qt = bid & 31;            // S/64 = 32 tiles
    const int h = (bid >> 5) & 31;
    const int b = bid >> 10;
    const int kv = h >> 2;              // NH/NKV = 4
    const int q0 = qt * 64;
    const int base = q0 - (WIN - 1);    // j=0 maps to key q0-127
    const int t = threadIdx.x;

    // Stage K (transposed) and V: 192 keys x 64 dims, 16B chunks
    for (int c = t; c < SPAN * 8; c += 256) {
        int j = c >> 3;
        int d0 = (c & 7) * 8;
        int kg = base + j;
        uint4 kk = {0, 0, 0, 0};
        uint4 vv = {0, 0, 0, 0};
        if (kg >= 0 && kg < SS) {
            long off = ((((long)b * SS + kg) * NKV + kv) * HD) + d0;
            kk = *(const uint4*)(k + off);
            vv = *(const uint4*)(v + off);
        }
        const __hip_bfloat16* kp = (const __hip_bfloat16*)&kk;
        const __hip_bfloat16* vp = (const __hip_bfloat16*)&vv;
        for (int u = 0; u < 8; u++) {
            Kt[d0 + u][j] = kp[u];
            Vs[j][d0 + u] = vp[u];
        }
    }
    // Stage Q tile
    for (int c = t; c < 64 * HD; c += 256) {
        int r = c >> 6;
        int d = c & 63;
        Ql[r][d] = q[((((long)b * SS + q0 + r) * NH + h) * HD) + d];
    }
    __syncthreads();

    const int w = t >> 6;
    const int lane = t & 63;
    const float sinkv = sinks[h];

    for (int rr = 0; rr < 16; rr++) {
        int r = w * 16 + rr;
        int qg = q0 + r;
        // window keys for row r: j in [r, r+127]; lane owns j1=r+lane, j2=j1+64
        int j1 = r + lane;
        int j2 = j1 + 64;
        int kg1 = base + j1;
        int kg2 = base + j2;

        float acc1 = 0.f, acc2 = 0.f;
        #pragma unroll 8
        for (int d = 0; d < HD; d++) {
            float qd = (float)Ql[r][d];
            acc1 += qd * (float)Kt[d][j1];
            acc2 += qd * (float)Kt[d][j2];
        }
        acc1 *= SCALE;
        acc2 *= SCALE;

        bool v1 = (kg1 >= 0) && (amask[b * SS + (kg1 >= 0 ? kg1 : 0)] > 0);
        bool v2 = (kg2 >= 0) && (amask[b * SS + (kg2 >= 0 ? kg2 : 0)] > 0);
        if (!v1) acc1 = -1e30f;
        if (!v2) acc2 = -1e30f;

        float m = fmaxf(acc1, acc2);
        for (int off = 32; off; off >>= 1) m = fmaxf(m, __shfl_xor(m, off));
        m = fmaxf(m, sinkv);

        float e1 = v1 ? __expf(acc1 - m) : 0.f;
        float e2 = v2 ? __expf(acc2 - m) : 0.f;
        float ssum = e1 + e2;
        for (int off = 32; off; off >>= 1) ssum += __shfl_xor(ssum, off);
        ssum += __expf(sinkv - m);   // softmax over [window, sink]; sink col dropped
        float inv = 1.0f / ssum;

        float p1 = e1 * inv;
        float p2 = e2 * inv;
        Pl[w][lane] = p1;
        Pl[w][64 + lane] = p2;
        // wave-internal LDS round-trip: single wave in lockstep; compiler
        // preserves ds_write->ds_read order (same array, may-alias)

        float o = 0.f;
        #pragma unroll 8
        for (int idx = 0; idx < 128; idx++) {
            o += Pl[w][idx] * (float)Vs[r + idx][lane];
        }
        ao[((((long)b * SS + qg) * NH + h) * HD) + lane] = __hip_bfloat16(o);
    }
}

// ---------------------------------------------------------------------------
// Zero d_ws usage. Scratch plan (fp32 d_out = 33.5 MB):
//   q (16.8 MB bf16)       -> d_out        [overwritten by final fp32 GEMM]
//   k,v (4.2 MB each bf16) -> wq region (16.8 MB fp32, dead after step 1;
//                             harness restores d_in before every launch)
//   attn_out (16.8 MB bf16)-> x region (33.5 MB fp32, dead after QKV gemms)
//   final GEMM reads attn_out (x region) + wo, writes d_out as FP32.
// Single stream => sequential; no dispatch reads and writes the same buffer.
// ---------------------------------------------------------------------------
extern "C" void kernel_launch(void* const* d_in, const int* in_sizes, int n_in,
                              void* d_out, int out_size, void* d_ws, size_t ws_size,
                              hipStream_t stream) {
    const float* x     = (const float*)d_in[0];
    const int*   am    = (const int*)d_in[1];
    const float* wq    = (const float*)d_in[2];
    const float* wk    = (const float*)d_in[3];
    const float* wv    = (const float*)d_in[4];
    const float* wo    = (const float*)d_in[5];
    const float* qnw   = (const float*)d_in[6];
    const float* knw   = (const float*)d_in[7];
    const float* sinks = (const float*)d_in[8];
    float* out = (float*)d_out;                                   // fp32 output!

    __hip_bfloat16* qbuf = (__hip_bfloat16*)d_out;                // 4096x2048 bf16 (16.8 MB)
    __hip_bfloat16* kbuf = (__hip_bfloat16*)wq;                   // 4096x512  bf16 (4.2 MB)
    __hip_bfloat16* vbuf = kbuf + (long)M_ROWS * (NKV * HD);      // 4096x512  bf16 (4.2 MB)
    __hip_bfloat16* abuf = (__hip_bfloat16*)x;                    // 4096x2048 bf16 (16.8 MB)

    // 1. Q projection (reads x, wq; writes bf16 q into d_out). wq dead after.
    gemm_bt<float, float, __hip_bfloat16>
        <<<dim3((NH * HD) / 64, M_ROWS / 64), 256, 0, stream>>>(
        x, wq, qbuf, M_ROWS, NH * HD, EMBED);
    // 2. K, V projections (read x; write into dead wq buffer).
    gemm_bt<float, float, __hip_bfloat16>
        <<<dim3((NKV * HD) / 64, M_ROWS / 64), 256, 0, stream>>>(
        x, wk, kbuf, M_ROWS, NKV * HD, EMBED);
    gemm_bt<float, float, __hip_bfloat16>
        <<<dim3((NKV * HD) / 64, M_ROWS / 64), 256, 0, stream>>>(
        x, wv, vbuf, M_ROWS, NKV * HD, EMBED);

    // 3. RMSNorm + RoPE on q and k (in place)
    int rows = BB * SS * NH + BB * SS * NKV;   // 163840
    norm_rope<<<rows / 4, 256, 0, stream>>>(qbuf, kbuf, qnw, knw);

    // 4. Sliding-window attention with sink (writes attn_out into dead x buffer)
    attn<<<BB * NH * (SS / 64), 256, 0, stream>>>(qbuf, kbuf, vbuf, am, sinks, abuf);

    // 5. Output projection: fp32 result into d_out (q dead; reads x region + wo)
    gemm_bt<__hip_bfloat16, float, float>
        <<<dim3(EMBED / 64, M_ROWS / 64), 256, 0, stream>>>(
        abuf, wo, out, M_ROWS, EMBED, EMBED);
}

// Round 7
// 560.961 us; speedup vs baseline: 1.9804x; 1.9804x over previous
//
#include <hip/hip_runtime.h>
#include <hip/hip_bf16.h>

// Problem constants. Harness: fp32 inputs, fp32 output buffer.
constexpr int BB = 2;
constexpr int SS = 2048;
constexpr int EMBED = 2048;
constexpr int NH = 32;
constexpr int NKV = 8;
constexpr int HD = 64;
constexpr int WIN = 128;      // sliding window
constexpr int M_ROWS = BB * SS;          // 4096
constexpr float SCALE = 0.125f;          // HD^-0.5

typedef __bf16 bf16x8 __attribute__((ext_vector_type(8)));
typedef float f32x4 __attribute__((ext_vector_type(4)));

__device__ inline uint4 cvt8(float4 lo, float4 hi) {
    union { __hip_bfloat16 h[8]; uint4 u; } r;
    r.h[0] = __hip_bfloat16(lo.x); r.h[1] = __hip_bfloat16(lo.y);
    r.h[2] = __hip_bfloat16(lo.z); r.h[3] = __hip_bfloat16(lo.w);
    r.h[4] = __hip_bfloat16(hi.x); r.h[5] = __hip_bfloat16(hi.y);
    r.h[6] = __hip_bfloat16(hi.z); r.h[7] = __hip_bfloat16(hi.w);
    return r.u;
}
__device__ inline uint4 load8(const float* p) {
    float4 lo = *(const float4*)p;
    float4 hi = *(const float4*)(p + 4);
    return cvt8(lo, hi);
}
__device__ inline uint4 load8(const __hip_bfloat16* p) {
    return *(const uint4*)p;
}

// ---------------------------------------------------------------------------
// fp32 -> bf16 bulk convert. n must be a multiple of 2048 (grid = n/2048).
// ---------------------------------------------------------------------------
__global__ __launch_bounds__(256) void cvt_bf16(
    const float* __restrict__ in, __hip_bfloat16* __restrict__ out, long n)
{
    long i = ((long)blockIdx.x * 256 + threadIdx.x) * 8;
    if (i + 8 <= n) *(uint4*)(out + i) = load8(in + i);
}

// ---------------------------------------------------------------------------
// C[M][N] = A[M][K] * B[N][K]^T. bf16 (or fp32, converted in staging) in,
// fp32 MFMA accum, TC out. Block = 256 = 4 waves, tile 64x64, BK=32.
// (Verified in round 6.)
// ---------------------------------------------------------------------------
template <typename TA, typename TB, typename TC>
__global__ __launch_bounds__(256) void gemm_bt(
    const TA* __restrict__ A,
    const TB* __restrict__ Bm,
    TC* __restrict__ C,
    int M, int N, int K)
{
    __shared__ uint4 As[4 * 64];
    __shared__ uint4 Bs[4 * 64];

    const int t = threadIdx.x;
    const int lane = t & 63;
    const int w = t >> 6;
    const int wr = (w >> 1) * 32;
    const int wc = (w & 1) * 32;
    const int srow = t & 63;
    const int squad = t >> 6;
    const long blockM = (long)blockIdx.y * 64;
    const long blockN = (long)blockIdx.x * 64;

    f32x4 acc[2][2] = {};

    const TA* Arow = A + (blockM + srow) * (long)K + squad * 8;
    const TB* Brow = Bm + (blockN + srow) * (long)K + squad * 8;

    const int lquad = lane >> 4;
    const int lrow = lane & 15;

    for (int k0 = 0; k0 < K; k0 += 32) {
        As[squad * 64 + srow] = load8(Arow + k0);
        Bs[squad * 64 + srow] = load8(Brow + k0);
        __syncthreads();

        bf16x8 a0 = *(const bf16x8*)&As[lquad * 64 + wr + lrow];
        bf16x8 a1 = *(const bf16x8*)&As[lquad * 64 + wr + 16 + lrow];
        bf16x8 b0 = *(const bf16x8*)&Bs[lquad * 64 + wc + lrow];
        bf16x8 b1 = *(const bf16x8*)&Bs[lquad * 64 + wc + 16 + lrow];

        acc[0][0] = __builtin_amdgcn_mfma_f32_16x16x32_bf16(a0, b0, acc[0][0], 0, 0, 0);
        acc[0][1] = __builtin_amdgcn_mfma_f32_16x16x32_bf16(a0, b1, acc[0][1], 0, 0, 0);
        acc[1][0] = __builtin_amdgcn_mfma_f32_16x16x32_bf16(a1, b0, acc[1][0], 0, 0, 0);
        acc[1][1] = __builtin_amdgcn_mfma_f32_16x16x32_bf16(a1, b1, acc[1][1], 0, 0, 0);
        __syncthreads();
    }

    for (int mi = 0; mi < 2; mi++)
        for (int ni = 0; ni < 2; ni++)
            for (int r = 0; r < 4; r++) {
                long rr = blockM + wr + mi * 16 + lquad * 4 + r;
                long cc = blockN + wc + ni * 16 + lrow;
                C[rr * N + cc] = TC(acc[mi][ni][r]);
            }
}

// ---------------------------------------------------------------------------
// Per-head RMSNorm + RoPE, in place. (Verified in round 6.)
// ---------------------------------------------------------------------------
__global__ __launch_bounds__(256) void norm_rope(
    __hip_bfloat16* __restrict__ q,
    __hip_bfloat16* __restrict__ k,
    const float* __restrict__ qw,
    const float* __restrict__ kw)
{
    const int QROWS = BB * SS * NH;
    int gid = blockIdx.x * 4 + (threadIdx.x >> 6);
    int lane = threadIdx.x & 63;

    __hip_bfloat16* base;
    const float* wptr;
    int s;
    if (gid < QROWS) {
        base = q + (long)gid * HD;
        s = (gid / NH) % SS;
        wptr = qw;
    } else {
        int g = gid - QROWS;
        base = k + (long)g * HD;
        s = (g / NKV) % SS;
        wptr = kw;
    }

    float x = (float)base[lane];
    float ss = x * x;
    for (int off = 32; off; off >>= 1) ss += __shfl_xor(ss, off);
    float scale = rsqrtf(ss * (1.0f / 64.0f) + 1e-6f);
    float xn = x * scale * wptr[lane];

    float partner = __shfl_xor(xn, 32);
    int i = lane & 31;
    float ang = (float)s * powf(10000.0f, -(float)i * (1.0f / 32.0f));
    float sn, cs;
    sincosf(ang, &sn, &cs);
    float y = (lane < 32) ? (xn * cs - partner * sn) : (xn * cs + partner * sn);
    base[lane] = __hip_bfloat16(y);
}

// ---------------------------------------------------------------------------
// MFMA sliding-window attention with sink. One block per (b, h, 64-q-tile).
//   S[64][192] = Q·K^T   (A-frags from global q; K staged [j][KROW])
//   softmax in regs (quad-local shfl reductions, rows = quad*4+reg)
//   P -> LDS (bf16, overlapping Ks region), O[64][64] = P·V (V staged [d][PROW])
// Verified MFMA conventions from round-6 gemm: A[m=lane&15][k=quad*8+j],
// B[n=lane&15][k=quad*8+j], D col=lane&15, row=quad*4+reg.
// ---------------------------------------------------------------------------
constexpr int SPAN = 192;    // keys [q0-127 .. q0+64]; j=191 always masked
constexpr int KROW = 72;     // Ks row stride (bf16): 144B -> 2-way-free banks
constexpr int PROW = 200;    // Ps/Vt row stride: 400B -> 2-way-free banks

__global__ __launch_bounds__(256) void attn_mfma(
    const __hip_bfloat16* __restrict__ q,
    const __hip_bfloat16* __restrict__ k,
    const __hip_bfloat16* __restrict__ v,
    const int* __restrict__ amask,
    const float* __restrict__ sinks,
    __hip_bfloat16* __restrict__ ao)
{
    __shared__ __hip_bfloat16 KsPs[SPAN * KROW];   // 13824 bf16; Ps needs 64*200=12800
    __shared__ __hip_bfloat16 Vt[64 * PROW];       // 12800 bf16
    // total LDS = 53248 B -> 3 blocks/CU

    const int bid = blockIdx.x;
    const int qt = bid & 31;
    const int h = (bid >> 5) & 31;
    const int b = bid >> 10;
    const int kv = h >> 2;
    const int q0 = qt * 64;
    const int base = q0 - (WIN - 1);
    const int t = threadIdx.x;
    const int w = t >> 6;
    const int lane = t & 63;
    const int lrow = lane & 15;
    const int quad = lane >> 4;

    // ---- stage K [j][d] and V^T [d][j] ----
    for (int c = t; c < SPAN * 8; c += 256) {
        int j = c >> 3;
        int d0 = (c & 7) * 8;
        int kg = base + j;
        uint4 kk = {0, 0, 0, 0}, vv = {0, 0, 0, 0};
        if (kg >= 0 && kg < SS) {
            long off = ((((long)b * SS + kg) * NKV + kv) * HD) + d0;
            kk = *(const uint4*)(k + off);
            vv = *(const uint4*)(v + off);
        }
        *(uint4*)&KsPs[j * KROW + d0] = kk;
        const __hip_bfloat16* vp = (const __hip_bfloat16*)&vv;
        #pragma unroll
        for (int u = 0; u < 8; u++) Vt[(d0 + u) * PROW + j] = vp[u];
    }
    __syncthreads();

    // ---- Q A-frags straight from global (lane m = lrow, k = quad*8) ----
    const __hip_bfloat16* qrow =
        q + (((long)b * SS + q0 + w * 16 + lrow) * NH + h) * HD;
    bf16x8 qa0 = *(const bf16x8*)(qrow + quad * 8);
    bf16x8 qa1 = *(const bf16x8*)(qrow + 32 + quad * 8);

    // ---- S = Q·K^T : 12 n-tiles, 2 k-steps ----
    f32x4 s[12] = {};
    #pragma unroll
    for (int ni = 0; ni < 12; ni++) {
        bf16x8 kb0 = *(const bf16x8*)&KsPs[(ni * 16 + lrow) * KROW + quad * 8];
        bf16x8 kb1 = *(const bf16x8*)&KsPs[(ni * 16 + lrow) * KROW + 32 + quad * 8];
        s[ni] = __builtin_amdgcn_mfma_f32_16x16x32_bf16(qa0, kb0, s[ni], 0, 0, 0);
        s[ni] = __builtin_amdgcn_mfma_f32_16x16x32_bf16(qa1, kb1, s[ni], 0, 0, 0);
    }

    // ---- per-lane key validity (col j = ni*16 + lrow) ----
    bool jok[12];
    #pragma unroll
    for (int ni = 0; ni < 12; ni++) {
        int kg = base + ni * 16 + lrow;
        jok[ni] = (kg >= 0) && (kg < SS) && (amask[b * SS + (kg >= 0 && kg < SS ? kg : 0)] > 0);
    }

    const float sinkv = sinks[h];

    // ---- masked softmax with sink, rows = w*16 + quad*4 + reg ----
    #pragma unroll
    for (int reg = 0; reg < 4; reg++) {
        int row = w * 16 + quad * 4 + reg;
        float mrow = -3.0e30f;
        #pragma unroll
        for (int ni = 0; ni < 12; ni++) {
            int j = ni * 16 + lrow;
            bool valid = jok[ni] && (j >= row) && (j <= row + 127);
            float val = valid ? s[ni][reg] * SCALE : -1.0e30f;
            s[ni][reg] = val;
            mrow = fmaxf(mrow, val);
        }
        #pragma unroll
        for (int off = 1; off < 16; off <<= 1) mrow = fmaxf(mrow, __shfl_xor(mrow, off));
        mrow = fmaxf(mrow, sinkv);
        float sum = 0.f;
        #pragma unroll
        for (int ni = 0; ni < 12; ni++) {
            float e = __expf(s[ni][reg] - mrow);   // -1e30 - m underflows to 0
            s[ni][reg] = e;
            sum += e;
        }
        #pragma unroll
        for (int off = 1; off < 16; off <<= 1) sum += __shfl_xor(sum, off);
        sum += __expf(sinkv - mrow);
        float inv = 1.0f / sum;
        #pragma unroll
        for (int ni = 0; ni < 12; ni++) s[ni][reg] *= inv;
    }

    __syncthreads();   // all waves done reading Ks before P overwrites it

    // ---- P -> LDS (C-layout scatter) ----
    #pragma unroll
    for (int ni = 0; ni < 12; ni++)
        #pragma unroll
        for (int reg = 0; reg < 4; reg++)
            KsPs[(w * 16 + quad * 4 + reg) * PROW + ni * 16 + lrow] =
                __hip_bfloat16(s[ni][reg]);
    __syncthreads();

    // ---- O = P·V : 4 n-tiles (d), 6 k-steps (j) ----
    f32x4 o[4] = {};
    #pragma unroll
    for (int ks = 0; ks < 6; ks++) {
        bf16x8 pa = *(const bf16x8*)&KsPs[(w * 16 + lrow) * PROW + ks * 32 + quad * 8];
        #pragma unroll
        for (int ni = 0; ni < 4; ni++) {
            bf16x8 vb = *(const bf16x8*)&Vt[(ni * 16 + lrow) * PROW + ks * 32 + quad * 8];
            o[ni] = __builtin_amdgcn_mfma_f32_16x16x32_bf16(pa, vb, o[ni], 0, 0, 0);
        }
    }

    // ---- epilogue ----
    #pragma unroll
    for (int ni = 0; ni < 4; ni++)
        #pragma unroll
        for (int reg = 0; reg < 4; reg++) {
            int row = w * 16 + quad * 4 + reg;
            ao[(((long)b * SS + q0 + row) * NH + h) * HD + ni * 16 + lrow] =
                __hip_bfloat16(o[ni][reg]);
        }
}

// ---------------------------------------------------------------------------
// Zero d_ws. Scratch plan (byte offsets; harness restores d_in every launch):
//   d_out (33.5MB fp32): xb[0:16.8M) wqb[16.8:25.2M) wkb[25.2:27.3M)
//                        wvb[27.3:29.4M)  -- all dead before final fp32 GEMM
//   x region (33.5MB):   q[0:16.8M), attn_out[16.8:33.5M)   (x dead after cvt)
//   wk/wv regions:       k, v (bf16, exact fit; dead after their cvt)
//   wq region:           wob (dead after Q-GEMM)
// ---------------------------------------------------------------------------
extern "C" void kernel_launch(void* const* d_in, const int* in_sizes, int n_in,
                              void* d_out, int out_size, void* d_ws, size_t ws_size,
                              hipStream_t stream) {
    const float* x     = (const float*)d_in[0];
    const int*   am    = (const int*)d_in[1];
    const float* wq    = (const float*)d_in[2];
    const float* wk    = (const float*)d_in[3];
    const float* wv    = (const float*)d_in[4];
    const float* wo    = (const float*)d_in[5];
    const float* qnw   = (const float*)d_in[6];
    const float* knw   = (const float*)d_in[7];
    const float* sinks = (const float*)d_in[8];
    float* out = (float*)d_out;

    __hip_bfloat16* xb   = (__hip_bfloat16*)d_out;
    __hip_bfloat16* wqb  = (__hip_bfloat16*)((char*)d_out + 16777216);
    __hip_bfloat16* wkb  = (__hip_bfloat16*)((char*)d_out + 25165824);
    __hip_bfloat16* wvb  = (__hip_bfloat16*)((char*)d_out + 27262976);
    __hip_bfloat16* qbuf = (__hip_bfloat16*)x;
    __hip_bfloat16* abuf = (__hip_bfloat16*)((char*)x + 16777216);
    __hip_bfloat16* kbuf = (__hip_bfloat16*)wk;
    __hip_bfloat16* vbuf = (__hip_bfloat16*)wv;
    __hip_bfloat16* wob  = (__hip_bfloat16*)wq;

    const long NX = (long)M_ROWS * EMBED;          // 8388608
    const long NW = (long)EMBED * EMBED;           // 4194304
    const long NWK = (long)(NKV * HD) * EMBED;     // 1048576

    cvt_bf16<<<NX / 2048, 256, 0, stream>>>(x, xb, NX);
    cvt_bf16<<<NW / 2048, 256, 0, stream>>>(wq, wqb, NW);

    gemm_bt<__hip_bfloat16, __hip_bfloat16, __hip_bfloat16>
        <<<dim3((NH * HD) / 64, M_ROWS / 64), 256, 0, stream>>>(
        xb, wqb, qbuf, M_ROWS, NH * HD, EMBED);

    cvt_bf16<<<NWK / 2048, 256, 0, stream>>>(wk, wkb, NWK);
    gemm_bt<__hip_bfloat16, __hip_bfloat16, __hip_bfloat16>
        <<<dim3((NKV * HD) / 64, M_ROWS / 64), 256, 0, stream>>>(
        xb, wkb, kbuf, M_ROWS, NKV * HD, EMBED);

    cvt_bf16<<<NWK / 2048, 256, 0, stream>>>(wv, wvb, NWK);
    gemm_bt<__hip_bfloat16, __hip_bfloat16, __hip_bfloat16>
        <<<dim3((NKV * HD) / 64, M_ROWS / 64), 256, 0, stream>>>(
        xb, wvb, vbuf, M_ROWS, NKV * HD, EMBED);

    int rows = BB * SS * NH + BB * SS * NKV;
    norm_rope<<<rows / 4, 256, 0, stream>>>(qbuf, kbuf, qnw, knw);

    attn_mfma<<<BB * NH * (SS / 64), 256, 0, stream>>>(
        qbuf, kbuf, vbuf, am, sinks, abuf);

    cvt_bf16<<<NW / 2048, 256, 0, stream>>>(wo, wob, NW);
    gemm_bt<__hip_bfloat16, __hip_bfloat16, float>
        <<<dim3(EMBED / 64, M_ROWS / 64), 256, 0, stream>>>(
        abuf, wob, out, M_ROWS, EMBED, EMBED);
}

// Round 8
// 437.971 us; speedup vs baseline: 2.5365x; 1.2808x over previous
//
#include <hip/hip_runtime.h>
#include <hip/hip_bf16.h>

// Problem constants. Harness: fp32 inputs, fp32 output buffer.
constexpr int BB = 2;
constexpr int SS = 2048;
constexpr int EMBED = 2048;
constexpr int NH = 32;
constexpr int NKV = 8;
constexpr int HD = 64;
constexpr int WIN = 128;      // sliding window
constexpr int M_ROWS = BB * SS;          // 4096
constexpr float SCALE = 0.125f;          // HD^-0.5

typedef __bf16 bf16x8 __attribute__((ext_vector_type(8)));
typedef float f32x4 __attribute__((ext_vector_type(4)));

__device__ inline uint4 cvt8(float4 lo, float4 hi) {
    union { __hip_bfloat16 h[8]; uint4 u; } r;
    r.h[0] = __hip_bfloat16(lo.x); r.h[1] = __hip_bfloat16(lo.y);
    r.h[2] = __hip_bfloat16(lo.z); r.h[3] = __hip_bfloat16(lo.w);
    r.h[4] = __hip_bfloat16(hi.x); r.h[5] = __hip_bfloat16(hi.y);
    r.h[6] = __hip_bfloat16(hi.z); r.h[7] = __hip_bfloat16(hi.w);
    return r.u;
}
__device__ inline uint4 load8(const float* p) {
    float4 lo = *(const float4*)p;
    float4 hi = *(const float4*)(p + 4);
    return cvt8(lo, hi);
}
__device__ inline uint4 load8(const __hip_bfloat16* p) {
    return *(const uint4*)p;
}

// async global->LDS, 16B per lane. LDS dest must be wave-uniform base +
// lane*16 (m97/m104 semantics) — our chunk index = w*64 + lane satisfies it.
__device__ inline void gload_lds16(const __hip_bfloat16* g, uint4* l) {
    __builtin_amdgcn_global_load_lds(
        (const __attribute__((address_space(1))) void*)g,
        (__attribute__((address_space(3))) void*)l, 16, 0, 0);
}

// ---------------------------------------------------------------------------
// fp32 -> bf16 bulk convert. n multiple of 2048 (grid = n/2048).
// ---------------------------------------------------------------------------
__global__ __launch_bounds__(256) void cvt_bf16(
    const float* __restrict__ in, __hip_bfloat16* __restrict__ out, long n)
{
    long i = ((long)blockIdx.x * 256 + threadIdx.x) * 8;
    if (i + 8 <= n) *(uint4*)(out + i) = load8(in + i);
}

// ---------------------------------------------------------------------------
// BIG GEMM (m97 structure): C[M][N] = A[M][K]·B[N][K]^T, bf16 in, TC out.
// 256 threads = 4 waves (2x2), 128x128 tile, BK=32, 4x4 MFMA accs per wave.
// LDS [quad][row] 16B chunks staged via global_load_lds width 16.
// ---------------------------------------------------------------------------
template <typename TC>
__global__ __launch_bounds__(256) void gemm_big(
    const __hip_bfloat16* __restrict__ A,
    const __hip_bfloat16* __restrict__ Bm,
    TC* __restrict__ C, int M, int N, int K)
{
    __shared__ uint4 As[512];   // chunk c = quad*128 + row : A[row][k0+quad*8..+8]
    __shared__ uint4 Bs[512];

    const int t = threadIdx.x;
    const int lane = t & 63;
    const int w = t >> 6;
    const int wr = (w >> 1) * 64;
    const int wc = (w & 1) * 64;
    const int lrow = lane & 15;
    const int quad = lane >> 4;
    const long blockM = (long)blockIdx.y * 128;
    const long blockN = (long)blockIdx.x * 128;

    f32x4 acc[4][4] = {};

    // staging: thread t covers chunks c0 = t and c1 = t + 256
    const int c0 = t, c1 = t + 256;
    const __hip_bfloat16* pa0 = A + (blockM + (c0 & 127)) * (long)K + (c0 >> 7) * 8;
    const __hip_bfloat16* pa1 = A + (blockM + (c1 & 127)) * (long)K + (c1 >> 7) * 8;
    const __hip_bfloat16* pb0 = Bm + (blockN + (c0 & 127)) * (long)K + (c0 >> 7) * 8;
    const __hip_bfloat16* pb1 = Bm + (blockN + (c1 & 127)) * (long)K + (c1 >> 7) * 8;

    for (int k0 = 0; k0 < K; k0 += 32) {
        gload_lds16(pa0 + k0, &As[c0]);
        gload_lds16(pa1 + k0, &As[c1]);
        gload_lds16(pb0 + k0, &Bs[c0]);
        gload_lds16(pb1 + k0, &Bs[c1]);
        __syncthreads();   // compiler drains vmcnt before s_barrier

        bf16x8 af[4], bfr[4];
        #pragma unroll
        for (int mi = 0; mi < 4; mi++)
            af[mi] = *(const bf16x8*)&As[quad * 128 + wr + mi * 16 + lrow];
        #pragma unroll
        for (int ni = 0; ni < 4; ni++)
            bfr[ni] = *(const bf16x8*)&Bs[quad * 128 + wc + ni * 16 + lrow];

        #pragma unroll
        for (int mi = 0; mi < 4; mi++)
            #pragma unroll
            for (int ni = 0; ni < 4; ni++)
                acc[mi][ni] = __builtin_amdgcn_mfma_f32_16x16x32_bf16(
                    af[mi], bfr[ni], acc[mi][ni], 0, 0, 0);
        __syncthreads();
    }

    // C/D layout: col = lane&15, row = quad*4 + reg
    #pragma unroll
    for (int mi = 0; mi < 4; mi++)
        #pragma unroll
        for (int ni = 0; ni < 4; ni++)
            #pragma unroll
            for (int r = 0; r < 4; r++) {
                long rr = blockM + wr + mi * 16 + quad * 4 + r;
                long cc = blockN + wc + ni * 16 + lrow;
                C[rr * N + cc] = TC(acc[mi][ni][r]);
            }
}

// ---------------------------------------------------------------------------
// Small GEMM (64x64 tile) — kept for K/V projections (N=512: 128-tile grid
// would leave half the CUs idle). Verified in round 6.
// ---------------------------------------------------------------------------
template <typename TA, typename TB, typename TC>
__global__ __launch_bounds__(256) void gemm_bt(
    const TA* __restrict__ A,
    const TB* __restrict__ Bm,
    TC* __restrict__ C,
    int M, int N, int K)
{
    __shared__ uint4 As[4 * 64];
    __shared__ uint4 Bs[4 * 64];

    const int t = threadIdx.x;
    const int lane = t & 63;
    const int w = t >> 6;
    const int wr = (w >> 1) * 32;
    const int wc = (w & 1) * 32;
    const int srow = t & 63;
    const int squad = t >> 6;
    const long blockM = (long)blockIdx.y * 64;
    const long blockN = (long)blockIdx.x * 64;

    f32x4 acc[2][2] = {};

    const TA* Arow = A + (blockM + srow) * (long)K + squad * 8;
    const TB* Brow = Bm + (blockN + srow) * (long)K + squad * 8;

    const int lquad = lane >> 4;
    const int lrow = lane & 15;

    for (int k0 = 0; k0 < K; k0 += 32) {
        As[squad * 64 + srow] = load8(Arow + k0);
        Bs[squad * 64 + srow] = load8(Brow + k0);
        __syncthreads();

        bf16x8 a0 = *(const bf16x8*)&As[lquad * 64 + wr + lrow];
        bf16x8 a1 = *(const bf16x8*)&As[lquad * 64 + wr + 16 + lrow];
        bf16x8 b0 = *(const bf16x8*)&Bs[lquad * 64 + wc + lrow];
        bf16x8 b1 = *(const bf16x8*)&Bs[lquad * 64 + wc + 16 + lrow];

        acc[0][0] = __builtin_amdgcn_mfma_f32_16x16x32_bf16(a0, b0, acc[0][0], 0, 0, 0);
        acc[0][1] = __builtin_amdgcn_mfma_f32_16x16x32_bf16(a0, b1, acc[0][1], 0, 0, 0);
        acc[1][0] = __builtin_amdgcn_mfma_f32_16x16x32_bf16(a1, b0, acc[1][0], 0, 0, 0);
        acc[1][1] = __builtin_amdgcn_mfma_f32_16x16x32_bf16(a1, b1, acc[1][1], 0, 0, 0);
        __syncthreads();
    }

    for (int mi = 0; mi < 2; mi++)
        for (int ni = 0; ni < 2; ni++)
            for (int r = 0; r < 4; r++) {
                long rr = blockM + wr + mi * 16 + lquad * 4 + r;
                long cc = blockN + wc + ni * 16 + lrow;
                C[rr * N + cc] = TC(acc[mi][ni][r]);
            }
}

// ---------------------------------------------------------------------------
// Per-head RMSNorm + RoPE, in place. (Verified round 6.)
// ---------------------------------------------------------------------------
__global__ __launch_bounds__(256) void norm_rope(
    __hip_bfloat16* __restrict__ q,
    __hip_bfloat16* __restrict__ k,
    const float* __restrict__ qw,
    const float* __restrict__ kw)
{
    const int QROWS = BB * SS * NH;
    int gid = blockIdx.x * 4 + (threadIdx.x >> 6);
    int lane = threadIdx.x & 63;

    __hip_bfloat16* base;
    const float* wptr;
    int s;
    if (gid < QROWS) {
        base = q + (long)gid * HD;
        s = (gid / NH) % SS;
        wptr = qw;
    } else {
        int g = gid - QROWS;
        base = k + (long)g * HD;
        s = (g / NKV) % SS;
        wptr = kw;
    }

    float x = (float)base[lane];
    float ss = x * x;
    for (int off = 32; off; off >>= 1) ss += __shfl_xor(ss, off);
    float scale = rsqrtf(ss * (1.0f / 64.0f) + 1e-6f);
    float xn = x * scale * wptr[lane];

    float partner = __shfl_xor(xn, 32);
    int i = lane & 31;
    float ang = (float)s * powf(10000.0f, -(float)i * (1.0f / 32.0f));
    float sn, cs;
    sincosf(ang, &sn, &cs);
    float y = (lane < 32) ? (xn * cs - partner * sn) : (xn * cs + partner * sn);
    base[lane] = __hip_bfloat16(y);
}

// ---------------------------------------------------------------------------
// MFMA sliding-window attention with sink. (Verified round 7.)
// ---------------------------------------------------------------------------
constexpr int SPAN = 192;
constexpr int KROW = 72;
constexpr int PROW = 200;

__global__ __launch_bounds__(256) void attn_mfma(
    const __hip_bfloat16* __restrict__ q,
    const __hip_bfloat16* __restrict__ k,
    const __hip_bfloat16* __restrict__ v,
    const int* __restrict__ amask,
    const float* __restrict__ sinks,
    __hip_bfloat16* __restrict__ ao)
{
    __shared__ __hip_bfloat16 KsPs[SPAN * KROW];
    __shared__ __hip_bfloat16 Vt[64 * PROW];

    const int bid = blockIdx.x;
    const int qt = bid & 31;
    const int h = (bid >> 5) & 31;
    const int b = bid >> 10;
    const int kv = h >> 2;
    const int q0 = qt * 64;
    const int base = q0 - (WIN - 1);
    const int t = threadIdx.x;
    const int w = t >> 6;
    const int lane = t & 63;
    const int lrow = lane & 15;
    const int quad = lane >> 4;

    for (int c = t; c < SPAN * 8; c += 256) {
        int j = c >> 3;
        int d0 = (c & 7) * 8;
        int kg = base + j;
        uint4 kk = {0, 0, 0, 0}, vv = {0, 0, 0, 0};
        if (kg >= 0 && kg < SS) {
            long off = ((((long)b * SS + kg) * NKV + kv) * HD) + d0;
            kk = *(const uint4*)(k + off);
            vv = *(const uint4*)(v + off);
        }
        *(uint4*)&KsPs[j * KROW + d0] = kk;
        const __hip_bfloat16* vp = (const __hip_bfloat16*)&vv;
        #pragma unroll
        for (int u = 0; u < 8; u++) Vt[(d0 + u) * PROW + j] = vp[u];
    }
    __syncthreads();

    const __hip_bfloat16* qrow =
        q + (((long)b * SS + q0 + w * 16 + lrow) * NH + h) * HD;
    bf16x8 qa0 = *(const bf16x8*)(qrow + quad * 8);
    bf16x8 qa1 = *(const bf16x8*)(qrow + 32 + quad * 8);

    f32x4 s[12] = {};
    #pragma unroll
    for (int ni = 0; ni < 12; ni++) {
        bf16x8 kb0 = *(const bf16x8*)&KsPs[(ni * 16 + lrow) * KROW + quad * 8];
        bf16x8 kb1 = *(const bf16x8*)&KsPs[(ni * 16 + lrow) * KROW + 32 + quad * 8];
        s[ni] = __builtin_amdgcn_mfma_f32_16x16x32_bf16(qa0, kb0, s[ni], 0, 0, 0);
        s[ni] = __builtin_amdgcn_mfma_f32_16x16x32_bf16(qa1, kb1, s[ni], 0, 0, 0);
    }

    bool jok[12];
    #pragma unroll
    for (int ni = 0; ni < 12; ni++) {
        int kg = base + ni * 16 + lrow;
        jok[ni] = (kg >= 0) && (kg < SS) && (amask[b * SS + (kg >= 0 && kg < SS ? kg : 0)] > 0);
    }

    const float sinkv = sinks[h];

    #pragma unroll
    for (int reg = 0; reg < 4; reg++) {
        int row = w * 16 + quad * 4 + reg;
        float mrow = -3.0e30f;
        #pragma unroll
        for (int ni = 0; ni < 12; ni++) {
            int j = ni * 16 + lrow;
            bool valid = jok[ni] && (j >= row) && (j <= row + 127);
            float val = valid ? s[ni][reg] * SCALE : -1.0e30f;
            s[ni][reg] = val;
            mrow = fmaxf(mrow, val);
        }
        #pragma unroll
        for (int off = 1; off < 16; off <<= 1) mrow = fmaxf(mrow, __shfl_xor(mrow, off));
        mrow = fmaxf(mrow, sinkv);
        float sum = 0.f;
        #pragma unroll
        for (int ni = 0; ni < 12; ni++) {
            float e = __expf(s[ni][reg] - mrow);
            s[ni][reg] = e;
            sum += e;
        }
        #pragma unroll
        for (int off = 1; off < 16; off <<= 1) sum += __shfl_xor(sum, off);
        sum += __expf(sinkv - mrow);
        float inv = 1.0f / sum;
        #pragma unroll
        for (int ni = 0; ni < 12; ni++) s[ni][reg] *= inv;
    }

    __syncthreads();

    #pragma unroll
    for (int ni = 0; ni < 12; ni++)
        #pragma unroll
        for (int reg = 0; reg < 4; reg++)
            KsPs[(w * 16 + quad * 4 + reg) * PROW + ni * 16 + lrow] =
                __hip_bfloat16(s[ni][reg]);
    __syncthreads();

    f32x4 o[4] = {};
    #pragma unroll
    for (int ks = 0; ks < 6; ks++) {
        bf16x8 pa = *(const bf16x8*)&KsPs[(w * 16 + lrow) * PROW + ks * 32 + quad * 8];
        #pragma unroll
        for (int ni = 0; ni < 4; ni++) {
            bf16x8 vb = *(const bf16x8*)&Vt[(ni * 16 + lrow) * PROW + ks * 32 + quad * 8];
            o[ni] = __builtin_amdgcn_mfma_f32_16x16x32_bf16(pa, vb, o[ni], 0, 0, 0);
        }
    }

    #pragma unroll
    for (int ni = 0; ni < 4; ni++)
        #pragma unroll
        for (int reg = 0; reg < 4; reg++) {
            int row = w * 16 + quad * 4 + reg;
            ao[(((long)b * SS + q0 + row) * NH + h) * HD + ni * 16 + lrow] =
                __hip_bfloat16(o[ni][reg]);
        }
}

// ---------------------------------------------------------------------------
// Zero d_ws. Scratch plan identical to round 7.
// ---------------------------------------------------------------------------
extern "C" void kernel_launch(void* const* d_in, const int* in_sizes, int n_in,
                              void* d_out, int out_size, void* d_ws, size_t ws_size,
                              hipStream_t stream) {
    const float* x     = (const float*)d_in[0];
    const int*   am    = (const int*)d_in[1];
    const float* wq    = (const float*)d_in[2];
    const float* wk    = (const float*)d_in[3];
    const float* wv    = (const float*)d_in[4];
    const float* wo    = (const float*)d_in[5];
    const float* qnw   = (const float*)d_in[6];
    const float* knw   = (const float*)d_in[7];
    const float* sinks = (const float*)d_in[8];
    float* out = (float*)d_out;

    __hip_bfloat16* xb   = (__hip_bfloat16*)d_out;
    __hip_bfloat16* wqb  = (__hip_bfloat16*)((char*)d_out + 16777216);
    __hip_bfloat16* wkb  = (__hip_bfloat16*)((char*)d_out + 25165824);
    __hip_bfloat16* wvb  = (__hip_bfloat16*)((char*)d_out + 27262976);
    __hip_bfloat16* qbuf = (__hip_bfloat16*)x;
    __hip_bfloat16* abuf = (__hip_bfloat16*)((char*)x + 16777216);
    __hip_bfloat16* kbuf = (__hip_bfloat16*)wk;
    __hip_bfloat16* vbuf = (__hip_bfloat16*)wv;
    __hip_bfloat16* wob  = (__hip_bfloat16*)wq;

    const long NX = (long)M_ROWS * EMBED;          // 8388608
    const long NW = (long)EMBED * EMBED;           // 4194304
    const long NWK = (long)(NKV * HD) * EMBED;     // 1048576

    cvt_bf16<<<NX / 2048, 256, 0, stream>>>(x, xb, NX);
    cvt_bf16<<<NW / 2048, 256, 0, stream>>>(wq, wqb, NW);

    gemm_big<__hip_bfloat16>
        <<<dim3((NH * HD) / 128, M_ROWS / 128), 256, 0, stream>>>(
        xb, wqb, qbuf, M_ROWS, NH * HD, EMBED);

    cvt_bf16<<<NWK / 2048, 256, 0, stream>>>(wk, wkb, NWK);
    gemm_bt<__hip_bfloat16, __hip_bfloat16, __hip_bfloat16>
        <<<dim3((NKV * HD) / 64, M_ROWS / 64), 256, 0, stream>>>(
        xb, wkb, kbuf, M_ROWS, NKV * HD, EMBED);

    cvt_bf16<<<NWK / 2048, 256, 0, stream>>>(wv, wvb, NWK);
    gemm_bt<__hip_bfloat16, __hip_bfloat16, __hip_bfloat16>
        <<<dim3((NKV * HD) / 64, M_ROWS / 64), 256, 0, stream>>>(
        xb, wvb, vbuf, M_ROWS, NKV * HD, EMBED);

    int rows = BB * SS * NH + BB * SS * NKV;
    norm_rope<<<rows / 4, 256, 0, stream>>>(qbuf, kbuf, qnw, knw);

    attn_mfma<<<BB * NH * (SS / 64), 256, 0, stream>>>(
        qbuf, kbuf, vbuf, am, sinks, abuf);

    cvt_bf16<<<NW / 2048, 256, 0, stream>>>(wo, wob, NW);
    gemm_big<float>
        <<<dim3(EMBED / 128, M_ROWS / 128), 256, 0, stream>>>(
        abuf, wob, out, M_ROWS, EMBED, EMBED);
}

// Round 9
// 388.685 us; speedup vs baseline: 2.8581x; 1.1268x over previous
//
#include <hip/hip_runtime.h>
#include <hip/hip_bf16.h>

// Problem constants. Harness: fp32 inputs, fp32 output buffer.
constexpr int BB = 2;
constexpr int SS = 2048;
constexpr int EMBED = 2048;
constexpr int NH = 32;
constexpr int NKV = 8;
constexpr int HD = 64;
constexpr int WIN = 128;
constexpr int M_ROWS = BB * SS;           // 4096
constexpr int QKVC = 3072;                // packed qkv columns
constexpr float SCALE = 0.125f;

typedef __bf16 bf16x8 __attribute__((ext_vector_type(8)));
typedef float f32x4 __attribute__((ext_vector_type(4)));

__device__ inline uint4 cvt8(float4 lo, float4 hi) {
    union { __hip_bfloat16 h[8]; uint4 u; } r;
    r.h[0] = __hip_bfloat16(lo.x); r.h[1] = __hip_bfloat16(lo.y);
    r.h[2] = __hip_bfloat16(lo.z); r.h[3] = __hip_bfloat16(lo.w);
    r.h[4] = __hip_bfloat16(hi.x); r.h[5] = __hip_bfloat16(hi.y);
    r.h[6] = __hip_bfloat16(hi.z); r.h[7] = __hip_bfloat16(hi.w);
    return r.u;
}
__device__ inline uint4 load8(const float* p) {
    float4 lo = *(const float4*)p;
    float4 hi = *(const float4*)(p + 4);
    return cvt8(lo, hi);
}

// async global->LDS, 16B per lane (wave-uniform base + lane*16).
__device__ inline void gload_lds16(const __hip_bfloat16* g, uint4* l) {
    __builtin_amdgcn_global_load_lds(
        (const __attribute__((address_space(1))) void*)g,
        (__attribute__((address_space(3))) void*)l, 16, 0, 0);
}

// ---------------------------------------------------------------------------
// prep: convert x -> xb and pack wq|wk|wv -> wqkv (bf16). 2048 elems/block.
// block ranges: x [0,4096), wq [4096,6144), wk [6144,6656), wv [6656,7168)
// ---------------------------------------------------------------------------
__global__ __launch_bounds__(256) void prep_cvt(
    const float* __restrict__ x,  const float* __restrict__ wq,
    const float* __restrict__ wk, const float* __restrict__ wv,
    __hip_bfloat16* __restrict__ xb, __hip_bfloat16* __restrict__ wqkv)
{
    long bid = blockIdx.x;
    const float* src; __hip_bfloat16* dst; long off;
    if (bid < 4096)      { src = x;  dst = xb;             off = bid * 2048; }
    else if (bid < 6144) { src = wq; dst = wqkv;           off = (bid - 4096) * 2048; }
    else if (bid < 6656) { src = wk; dst = wqkv + 4194304; off = (bid - 6144) * 2048; }
    else                 { src = wv; dst = wqkv + 5242880; off = (bid - 6656) * 2048; }
    long i = off + (long)threadIdx.x * 8;
    *(uint4*)(dst + i) = load8(src + i);
}

__global__ __launch_bounds__(256) void cvt_bf16(
    const float* __restrict__ in, __hip_bfloat16* __restrict__ out, long n)
{
    long i = ((long)blockIdx.x * 256 + threadIdx.x) * 8;
    if (i + 8 <= n) *(uint4*)(out + i) = load8(in + i);
}

// ---------------------------------------------------------------------------
// BIG GEMM (m97 structure): C[M][N] = A[M][K]·B[N][K]^T, bf16 in, TC out,
// C row stride ldc. 256 threads = 4 waves (2x2), 128x128 tile, BK=32.
// ---------------------------------------------------------------------------
template <typename TC>
__global__ __launch_bounds__(256) void gemm_big(
    const __hip_bfloat16* __restrict__ A,
    const __hip_bfloat16* __restrict__ Bm,
    TC* __restrict__ C, int K, int ldc)
{
    __shared__ uint4 As[512];   // chunk c = quad*128 + row
    __shared__ uint4 Bs[512];

    const int t = threadIdx.x;
    const int lane = t & 63;
    const int w = t >> 6;
    const int wr = (w >> 1) * 64;
    const int wc = (w & 1) * 64;
    const int lrow = lane & 15;
    const int quad = lane >> 4;
    const long blockM = (long)blockIdx.y * 128;
    const long blockN = (long)blockIdx.x * 128;

    f32x4 acc[4][4] = {};

    const int c0 = t, c1 = t + 256;
    const __hip_bfloat16* pa0 = A + (blockM + (c0 & 127)) * (long)K + (c0 >> 7) * 8;
    const __hip_bfloat16* pa1 = A + (blockM + (c1 & 127)) * (long)K + (c1 >> 7) * 8;
    const __hip_bfloat16* pb0 = Bm + (blockN + (c0 & 127)) * (long)K + (c0 >> 7) * 8;
    const __hip_bfloat16* pb1 = Bm + (blockN + (c1 & 127)) * (long)K + (c1 >> 7) * 8;

    for (int k0 = 0; k0 < K; k0 += 32) {
        gload_lds16(pa0 + k0, &As[c0]);
        gload_lds16(pa1 + k0, &As[c1]);
        gload_lds16(pb0 + k0, &Bs[c0]);
        gload_lds16(pb1 + k0, &Bs[c1]);
        __syncthreads();

        bf16x8 af[4], bfr[4];
        #pragma unroll
        for (int mi = 0; mi < 4; mi++)
            af[mi] = *(const bf16x8*)&As[quad * 128 + wr + mi * 16 + lrow];
        #pragma unroll
        for (int ni = 0; ni < 4; ni++)
            bfr[ni] = *(const bf16x8*)&Bs[quad * 128 + wc + ni * 16 + lrow];

        #pragma unroll
        for (int mi = 0; mi < 4; mi++)
            #pragma unroll
            for (int ni = 0; ni < 4; ni++)
                acc[mi][ni] = __builtin_amdgcn_mfma_f32_16x16x32_bf16(
                    af[mi], bfr[ni], acc[mi][ni], 0, 0, 0);
        __syncthreads();
    }

    #pragma unroll
    for (int mi = 0; mi < 4; mi++)
        #pragma unroll
        for (int ni = 0; ni < 4; ni++)
            #pragma unroll
            for (int r = 0; r < 4; r++) {
                long rr = blockM + wr + mi * 16 + quad * 4 + r;
                long cc = blockN + wc + ni * 16 + lrow;
                C[rr * (long)ldc + cc] = TC(acc[mi][ni][r]);
            }
}

// ---------------------------------------------------------------------------
// Per-head RMSNorm + RoPE, in place on packed qkv[row][3072].
// q: cols h*64, h<32; k: cols 2048 + kv*64.
// ---------------------------------------------------------------------------
__global__ __launch_bounds__(256) void norm_rope(
    __hip_bfloat16* __restrict__ qkv,
    const float* __restrict__ qw,
    const float* __restrict__ kw)
{
    const int QROWS = M_ROWS * NH;      // 131072
    int gid = blockIdx.x * 4 + (threadIdx.x >> 6);
    int lane = threadIdx.x & 63;

    __hip_bfloat16* base;
    const float* wptr;
    int s;
    if (gid < QROWS) {
        int row = gid >> 5;             // /NH
        base = qkv + (long)row * QKVC + (gid & 31) * HD;
        s = row % SS;
        wptr = qw;
    } else {
        int g = gid - QROWS;
        int row = g >> 3;               // /NKV
        base = qkv + (long)row * QKVC + 2048 + (g & 7) * HD;
        s = row % SS;
        wptr = kw;
    }

    float x = (float)base[lane];
    float ss = x * x;
    for (int off = 32; off; off >>= 1) ss += __shfl_xor(ss, off);
    float scale = rsqrtf(ss * (1.0f / 64.0f) + 1e-6f);
    float xn = x * scale * wptr[lane];

    float partner = __shfl_xor(xn, 32);
    int i = lane & 31;
    float ang = (float)s * powf(10000.0f, -(float)i * (1.0f / 32.0f));
    float sn, cs;
    sincosf(ang, &sn, &cs);
    float y = (lane < 32) ? (xn * cs - partner * sn) : (xn * cs + partner * sn);
    base[lane] = __hip_bfloat16(y);
}

// ---------------------------------------------------------------------------
// MFMA sliding-window attention with sink, reading packed qkv[row][3072].
// (Structure verified round 7; only addressing changed.)
// ---------------------------------------------------------------------------
constexpr int SPAN = 192;
constexpr int KROW = 72;
constexpr int PROW = 200;

__global__ __launch_bounds__(256) void attn_mfma(
    const __hip_bfloat16* __restrict__ qkv,
    const int* __restrict__ amask,
    const float* __restrict__ sinks,
    __hip_bfloat16* __restrict__ ao)     // [4096][2048] (b,s,h,d)
{
    __shared__ __hip_bfloat16 KsPs[SPAN * KROW];
    __shared__ __hip_bfloat16 Vt[64 * PROW];

    const int bid = blockIdx.x;
    const int qt = bid & 31;
    const int h = (bid >> 5) & 31;
    const int b = bid >> 10;
    const int kv = h >> 2;
    const int q0 = qt * 64;
    const int base = q0 - (WIN - 1);
    const int t = threadIdx.x;
    const int w = t >> 6;
    const int lane = t & 63;
    const int lrow = lane & 15;
    const int quad = lane >> 4;

    for (int c = t; c < SPAN * 8; c += 256) {
        int j = c >> 3;
        int d0 = (c & 7) * 8;
        int kg = base + j;
        uint4 kk = {0, 0, 0, 0}, vv = {0, 0, 0, 0};
        if (kg >= 0 && kg < SS) {
            long rowoff = ((long)b * SS + kg) * QKVC + kv * HD + d0;
            kk = *(const uint4*)(qkv + rowoff + 2048);
            vv = *(const uint4*)(qkv + rowoff + 2560);
        }
        *(uint4*)&KsPs[j * KROW + d0] = kk;
        const __hip_bfloat16* vp = (const __hip_bfloat16*)&vv;
        #pragma unroll
        for (int u = 0; u < 8; u++) Vt[(d0 + u) * PROW + j] = vp[u];
    }
    __syncthreads();

    const __hip_bfloat16* qrow =
        qkv + ((long)b * SS + q0 + w * 16 + lrow) * QKVC + h * HD;
    bf16x8 qa0 = *(const bf16x8*)(qrow + quad * 8);
    bf16x8 qa1 = *(const bf16x8*)(qrow + 32 + quad * 8);

    f32x4 s[12] = {};
    #pragma unroll
    for (int ni = 0; ni < 12; ni++) {
        bf16x8 kb0 = *(const bf16x8*)&KsPs[(ni * 16 + lrow) * KROW + quad * 8];
        bf16x8 kb1 = *(const bf16x8*)&KsPs[(ni * 16 + lrow) * KROW + 32 + quad * 8];
        s[ni] = __builtin_amdgcn_mfma_f32_16x16x32_bf16(qa0, kb0, s[ni], 0, 0, 0);
        s[ni] = __builtin_amdgcn_mfma_f32_16x16x32_bf16(qa1, kb1, s[ni], 0, 0, 0);
    }

    bool jok[12];
    #pragma unroll
    for (int ni = 0; ni < 12; ni++) {
        int kg = base + ni * 16 + lrow;
        jok[ni] = (kg >= 0) && (kg < SS) && (amask[b * SS + (kg >= 0 && kg < SS ? kg : 0)] > 0);
    }

    const float sinkv = sinks[h];

    #pragma unroll
    for (int reg = 0; reg < 4; reg++) {
        int row = w * 16 + quad * 4 + reg;
        float mrow = -3.0e30f;
        #pragma unroll
        for (int ni = 0; ni < 12; ni++) {
            int j = ni * 16 + lrow;
            bool valid = jok[ni] && (j >= row) && (j <= row + 127);
            float val = valid ? s[ni][reg] * SCALE : -1.0e30f;
            s[ni][reg] = val;
            mrow = fmaxf(mrow, val);
        }
        #pragma unroll
        for (int off = 1; off < 16; off <<= 1) mrow = fmaxf(mrow, __shfl_xor(mrow, off));
        mrow = fmaxf(mrow, sinkv);
        float sum = 0.f;
        #pragma unroll
        for (int ni = 0; ni < 12; ni++) {
            float e = __expf(s[ni][reg] - mrow);
            s[ni][reg] = e;
            sum += e;
        }
        #pragma unroll
        for (int off = 1; off < 16; off <<= 1) sum += __shfl_xor(sum, off);
        sum += __expf(sinkv - mrow);
        float inv = 1.0f / sum;
        #pragma unroll
        for (int ni = 0; ni < 12; ni++) s[ni][reg] *= inv;
    }

    __syncthreads();

    #pragma unroll
    for (int ni = 0; ni < 12; ni++)
        #pragma unroll
        for (int reg = 0; reg < 4; reg++)
            KsPs[(w * 16 + quad * 4 + reg) * PROW + ni * 16 + lrow] =
                __hip_bfloat16(s[ni][reg]);
    __syncthreads();

    f32x4 o[4] = {};
    #pragma unroll
    for (int ks = 0; ks < 6; ks++) {
        bf16x8 pa = *(const bf16x8*)&KsPs[(w * 16 + lrow) * PROW + ks * 32 + quad * 8];
        #pragma unroll
        for (int ni = 0; ni < 4; ni++) {
            bf16x8 vb = *(const bf16x8*)&Vt[(ni * 16 + lrow) * PROW + ks * 32 + quad * 8];
            o[ni] = __builtin_amdgcn_mfma_f32_16x16x32_bf16(pa, vb, o[ni], 0, 0, 0);
        }
    }

    #pragma unroll
    for (int ni = 0; ni < 4; ni++)
        #pragma unroll
        for (int reg = 0; reg < 4; reg++) {
            int row = w * 16 + quad * 4 + reg;
            ao[((long)b * SS + q0 + row) * (NH * HD) + h * HD + ni * 16 + lrow] =
                __hip_bfloat16(o[ni][reg]);
        }
}

// ---------------------------------------------------------------------------
// Zero d_ws. Scratch plan (harness restores d_in before every launch):
//   d_out (33.5MB): xb[0:16.8M) wqkv[16.8:29.4M)   -- dead before final GEMM
//   x region (33.5MB): qkv[0:25.2M) wob[25.2:33.5M) -- x dead after prep
//   wq region (16.8MB): abuf (attn output)          -- wq dead after prep
// Order: prep -> wo-cvt -> qkv-gemm -> norm -> attn -> final gemm.
// ---------------------------------------------------------------------------
extern "C" void kernel_launch(void* const* d_in, const int* in_sizes, int n_in,
                              void* d_out, int out_size, void* d_ws, size_t ws_size,
                              hipStream_t stream) {
    const float* x     = (const float*)d_in[0];
    const int*   am    = (const int*)d_in[1];
    const float* wq    = (const float*)d_in[2];
    const float* wk    = (const float*)d_in[3];
    const float* wv    = (const float*)d_in[4];
    const float* wo    = (const float*)d_in[5];
    const float* qnw   = (const float*)d_in[6];
    const float* knw   = (const float*)d_in[7];
    const float* sinks = (const float*)d_in[8];
    float* out = (float*)d_out;

    __hip_bfloat16* xb    = (__hip_bfloat16*)d_out;
    __hip_bfloat16* wqkv  = (__hip_bfloat16*)((char*)d_out + 16777216);
    __hip_bfloat16* qkv   = (__hip_bfloat16*)x;
    __hip_bfloat16* wob   = (__hip_bfloat16*)((char*)x + 25165824);
    __hip_bfloat16* abuf  = (__hip_bfloat16*)wq;

    const long NW = (long)EMBED * EMBED;   // 4194304

    // 1. convert x + pack wq|wk|wv (7168 blocks)
    prep_cvt<<<7168, 256, 0, stream>>>(x, wq, wk, wv, xb, wqkv);
    // 2. convert wo into dead x tail
    cvt_bf16<<<NW / 2048, 256, 0, stream>>>(wo, wob, NW);

    // 3. fused QKV projection: qkv[4096][3072], grid (24,32) = 768 blocks
    gemm_big<__hip_bfloat16>
        <<<dim3(QKVC / 128, M_ROWS / 128), 256, 0, stream>>>(
        xb, wqkv, qkv, EMBED, QKVC);

    // 4. RMSNorm + RoPE on q,k inside packed qkv
    int rows = M_ROWS * NH + M_ROWS * NKV;   // 163840
    norm_rope<<<rows / 4, 256, 0, stream>>>(qkv, qnw, knw);

    // 5. attention -> abuf [4096][2048]
    attn_mfma<<<BB * NH * (SS / 64), 256, 0, stream>>>(qkv, am, sinks, abuf);

    // 6. output projection: fp32 into d_out, grid (16,32)
    gemm_big<float>
        <<<dim3(EMBED / 128, M_ROWS / 128), 256, 0, stream>>>(
        abuf, wob, out, EMBED, EMBED);
}